// Round 3
// baseline (235.931 us; speedup 1.0000x reference)
//
#include <hip/hip_runtime.h>

#define FFT_N 4096
#define NEG_TWOPI -6.28318530717958647692f

// Kernel A: stages step=2..64 (intra-64-row-block butterflies).
// Loads fp32 x with the i^2048 row permutation, computes 6 stages in LDS,
// writes complex64 (interleaved float2) tiles to dst4 (2*N*N floats).
__global__ __launch_bounds__(256) void fft_lo(const float* __restrict__ x,
                                              const float* __restrict__ w,
                                              float4* __restrict__ dst4,
                                              unsigned dst_lim4) {
    __shared__ __align__(16) float2 tile[64 * 64];   // 32 KB
    const int t  = threadIdx.x;
    const int c0 = (blockIdx.x & 63) << 6;
    const int r0 = (blockIdx.x >> 6) << 6;
    const int src_r0 = r0 ^ 2048;      // initial permutation: new[i] = old[i^2048]

    const float4* x4    = (const float4*)x;        // row = 1024 float4
    float4*       tile4 = (float4*)tile;           // row = 32 float4
#pragma unroll
    for (int l = 0; l < 4; ++l) {
        int idx = l * 256 + t;                     // 0..1023
        int row = idx >> 4;                        // 64 rows
        int cg  = idx & 15;                        // 16 groups of 4 cols
        float4 v = x4[(size_t)(src_r0 + row) * 1024 + (c0 >> 2) + cg];
        tile4[(row << 5) + (cg << 1) + 0] = make_float4(v.x, 0.f, v.y, 0.f);
        tile4[(row << 5) + (cg << 1) + 1] = make_float4(v.z, 0.f, v.w, 0.f);
    }
    __syncthreads();

    const int c  = t & 63;    // column lane
    const int pb = t >> 6;    // wave id 0..3
#pragma unroll
    for (int step = 2; step <= 64; step <<= 1) {
        const int half = step >> 1;
        const int kmul = FFT_N / step;
#pragma unroll
        for (int q = 0; q < 8; ++q) {
            const int p    = pb * 8 + q;           // pair index 0..31
            const int blk  = p / half;
            const int r    = p - blk * half;
            const int itop = blk * step + r;
            const int k    = r * kmul;
            const float wk = w[(size_t)k * FFT_N + c0 + c];
            const float phase = NEG_TWOPI * ((float)k * (1.0f / 4096.0f)) * wk;
            float s, cs;
            __sincosf(phase, &s, &cs);
            float2 a = tile[(itop << 6) + c];
            float2 b = tile[((itop + half) << 6) + c];
            float tr = cs * b.x - s * b.y;
            float ti = cs * b.y + s * b.x;
            tile[(itop << 6) + c]          = make_float2(a.x + tr, a.y + ti);
            tile[((itop + half) << 6) + c] = make_float2(a.x - tr, a.y - ti);
        }
        __syncthreads();
    }

#pragma unroll
    for (int l = 0; l < 8; ++l) {
        int idx = l * 256 + t;                     // 0..2047
        int row = idx >> 5;
        int cp  = idx & 31;                        // 32 float4 per row
        size_t gi = (size_t)(r0 + row) * 2048 + (c0 >> 1) + cp;
        if (gi < dst_lim4) dst4[gi] = tile4[(row << 5) + cp];
    }
}

// Kernel B: stages step=128..4096 on rows {rres + 64*j}. Reads complex
// interleaved from src4; REAL_OUT=0 stores complex to dst (may be in-place
// with src), REAL_OUT=1 stores only real parts (N*N floats) to dst.
template <int REAL_OUT>
__global__ __launch_bounds__(256) void fft_hi(const float* __restrict__ w,
                                              const float4* __restrict__ src4,
                                              float4* __restrict__ dst4,
                                              unsigned src_lim4,
                                              unsigned dst_lim4) {
    __shared__ __align__(16) float2 tile[64 * 64];   // 32 KB
    const int t    = threadIdx.x;
    const int c0   = (blockIdx.x & 63) << 6;
    const int rres = blockIdx.x >> 6;  // row residue 0..63

    float4* tile4 = (float4*)tile;
#pragma unroll
    for (int l = 0; l < 8; ++l) {
        int idx = l * 256 + t;
        int j   = idx >> 5;
        int cp  = idx & 31;
        size_t gi = (size_t)(rres + (j << 6)) * 2048 + (c0 >> 1) + cp;
        tile4[(j << 5) + cp] = (gi < src_lim4) ? src4[gi]
                                               : make_float4(0.f, 0.f, 0.f, 0.f);
    }
    __syncthreads();

    const int c  = t & 63;
    const int pb = t >> 6;
#pragma unroll
    for (int h = 1; h <= 32; h <<= 1) {            // step_g = 128h
        const int kmul = 32 / h;                   // N / step_g
#pragma unroll
        for (int q = 0; q < 8; ++q) {
            const int p    = pb * 8 + q;
            const int blk  = p / h;
            const int r    = p - blk * h;
            const int jtop = blk * (h << 1) + r;
            const int k    = (rres + (r << 6)) * kmul;
            const float wk = w[(size_t)k * FFT_N + c0 + c];
            const float phase = NEG_TWOPI * ((float)k * (1.0f / 4096.0f)) * wk;
            float s, cs;
            __sincosf(phase, &s, &cs);
            float2 a = tile[(jtop << 6) + c];
            float2 b = tile[((jtop + h) << 6) + c];
            float tr = cs * b.x - s * b.y;
            float ti = cs * b.y + s * b.x;
            tile[(jtop << 6) + c]       = make_float2(a.x + tr, a.y + ti);
            tile[((jtop + h) << 6) + c] = make_float2(a.x - tr, a.y - ti);
        }
        __syncthreads();
    }

    if (REAL_OUT) {
        // Store only real parts: out is N*N floats, row-major (4096 cols).
#pragma unroll
        for (int l = 0; l < 4; ++l) {
            int idx = l * 256 + t;                 // 0..1023
            int j   = idx >> 4;
            int g   = idx & 15;                    // 16 float4 groups of 4 cols
            float4 v;
            v.x = tile[(j << 6) + 4 * g + 0].x;
            v.y = tile[(j << 6) + 4 * g + 1].x;
            v.z = tile[(j << 6) + 4 * g + 2].x;
            v.w = tile[(j << 6) + 4 * g + 3].x;
            size_t gi = (size_t)(rres + (j << 6)) * 1024 + (c0 >> 2) + g;
            if (gi < dst_lim4) dst4[gi] = v;
        }
    } else {
#pragma unroll
        for (int l = 0; l < 8; ++l) {
            int idx = l * 256 + t;
            int j   = idx >> 5;
            int cp  = idx & 31;
            size_t gi = (size_t)(rres + (j << 6)) * 2048 + (c0 >> 1) + cp;
            if (gi < dst_lim4) dst4[gi] = tile4[(j << 5) + cp];
        }
    }
}

extern "C" void kernel_launch(void* const* d_in, const int* in_sizes, int n_in,
                              void* d_out, int out_size, void* d_ws, size_t ws_size,
                              hipStream_t stream) {
    const float* x = (const float*)d_in[0];
    const float* w = (const float*)d_in[1];
    const long long NN = (long long)FFT_N * FFT_N;

    if ((long long)out_size >= 2 * NN) {
        // World 1: d_out is the complex64 buffer viewed as 2*N*N floats,
        // interleaved (re,im). Compute in-place in d_out.
        float4* o4 = (float4*)d_out;
        unsigned lim4 = (unsigned)(out_size / 4);
        fft_lo<<<4096, 256, 0, stream>>>(x, w, o4, lim4);
        fft_hi<0><<<4096, 256, 0, stream>>>(w, o4, o4, lim4, lim4);
    } else {
        // World 4: d_out holds N*N floats = real part only (harness cast
        // complex64 -> float32). Complex intermediate lives in d_ws.
        float4* ws4 = (float4*)d_ws;
        unsigned ws_lim4  = (unsigned)(ws_size / 16);   // float4 slots in ws
        unsigned out_lim4 = (unsigned)(out_size / 4);
        fft_lo<<<4096, 256, 0, stream>>>(x, w, ws4, ws_lim4);
        fft_hi<1><<<4096, 256, 0, stream>>>(w, (const float4*)ws4, (float4*)d_out,
                                            ws_lim4, out_lim4);
    }
}

// Round 5
// 216.954 us; speedup vs baseline: 1.0875x; 1.0875x over previous
//
#include <hip/hip_runtime.h>

#define NEG_TWOPI -6.28318530717958647692f

__device__ __forceinline__ void bf(float& ar, float& ai, float& br, float& bi,
                                   float s, float cs) {
    float tr = cs * br - s * bi;
    float ti = cs * bi + s * br;
    br = ar - tr; bi = ai - ti;
    ar = ar + tr; ai = ai + ti;
}

// Kernel A: stages step=2..64 (butterflies within aligned 64-row blocks).
// Global I/O: staged float4 tile load/store with bounds guards (round-3 proven
// pattern). Compute: register-resident, h=1..8 then one LDS ownership
// exchange, h=16,32. 3 barriers.
__global__ __launch_bounds__(256) void fft_lo(const float* __restrict__ x,
                                              const float* __restrict__ w,
                                              float4* __restrict__ dst4,
                                              unsigned dst_lim4) {
    __shared__ __align__(16) float2 tile[64 * 64];   // 32 KB, AoS (re,im)
    const int t  = threadIdx.x;
    const int c0 = (blockIdx.x & 63) << 6;
    const int r0 = (blockIdx.x >> 6) << 6;
    const int src_r0 = r0 ^ 2048;      // initial permutation: new[i] = old[i^2048]

    // Stage-in: 64 rows x 64 cols fp32, imag = 0 (float4, coalesced).
    const float4* x4    = (const float4*)x;        // row = 1024 float4
    float4*       tile4 = (float4*)tile;           // row = 32 float4
#pragma unroll
    for (int l = 0; l < 4; ++l) {
        int idx = l * 256 + t;                     // 0..1023
        int row = idx >> 4;
        int cg  = idx & 15;
        float4 v = x4[(size_t)(src_r0 + row) * 1024 + (c0 >> 2) + cg];
        tile4[(row << 5) + (cg << 1) + 0] = make_float4(v.x, 0.f, v.y, 0.f);
        tile4[(row << 5) + (cg << 1) + 1] = make_float4(v.z, 0.f, v.w, 0.f);
    }
    __syncthreads();                               // barrier 1

    const int c  = t & 63;
    const int pb = t >> 6;

    float ar[16], ai[16];
    // Rows 16*pb+m of this tile into registers. Read and later overwritten by
    // the SAME thread -> no extra barrier needed before the exchange write.
#pragma unroll
    for (int m = 0; m < 16; ++m) {
        float2 v = tile[(16 * pb + m) * 64 + c];
        ar[m] = v.x; ai[m] = v.y;
    }

    // Phase 1: h = 1,2,4,8 (steps 2..16). r==0 => identity twiddle.
#pragma unroll
    for (int h = 1; h <= 8; h <<= 1) {
        const int step = h << 1;
        const int kmul = 4096 / step;
#pragma unroll
        for (int r = 0; r < h; ++r) {
            float s = 0.f, cs = 1.f;
            if (r != 0) {
                const int k = r * kmul;
                const float wk = w[(size_t)k * 4096 + c0 + c];
                __sincosf(NEG_TWOPI * ((float)k * (1.f / 4096.f)) * wk, &s, &cs);
            }
#pragma unroll
            for (int b = 0; b < 8 / h; ++b) {
                const int mt = b * step + r;
                bf(ar[mt], ai[mt], ar[mt + h], ai[mt + h], s, cs);
            }
        }
    }

    // Ownership exchange: consecutive-16 -> stride-4 (j = pb + 4m).
#pragma unroll
    for (int m = 0; m < 16; ++m)
        tile[(16 * pb + m) * 64 + c] = make_float2(ar[m], ai[m]);
    __syncthreads();                               // barrier 2
#pragma unroll
    for (int m = 0; m < 16; ++m) {
        float2 v = tile[(pb + 4 * m) * 64 + c];
        ar[m] = v.x; ai[m] = v.y;
    }

    // Phase 2: step 32 (pairs m,m+4) and step 64 (pairs m,m+8).
#pragma unroll
    for (int rm = 0; rm < 4; ++rm) {
        const int j = pb + 4 * rm;                 // j_top mod 16
        const int k = j * 128;
        float s, cs;
        const float wk = w[(size_t)k * 4096 + c0 + c];
        __sincosf(NEG_TWOPI * ((float)k * (1.f / 4096.f)) * wk, &s, &cs);
#pragma unroll
        for (int b = 0; b < 2; ++b) {
            const int mt = b * 8 + rm;
            bf(ar[mt], ai[mt], ar[mt + 4], ai[mt + 4], s, cs);
        }
    }
#pragma unroll
    for (int m = 0; m < 8; ++m) {
        const int j = pb + 4 * m;                  // j_top mod 32
        const int k = j * 64;
        float s, cs;
        const float wk = w[(size_t)k * 4096 + c0 + c];
        __sincosf(NEG_TWOPI * ((float)k * (1.f / 4096.f)) * wk, &s, &cs);
        bf(ar[m], ai[m], ar[m + 8], ai[m + 8], s, cs);
    }

    // Write results back to own addresses (same thread read them), barrier,
    // then round-3 float4 guarded stage-out.
#pragma unroll
    for (int m = 0; m < 16; ++m)
        tile[(pb + 4 * m) * 64 + c] = make_float2(ar[m], ai[m]);
    __syncthreads();                               // barrier 3
#pragma unroll
    for (int l = 0; l < 8; ++l) {
        int idx = l * 256 + t;                     // 0..2047
        int row = idx >> 5;
        int cp  = idx & 31;
        size_t gi = (size_t)(r0 + row) * 2048 + (c0 >> 1) + cp;
        if (gi < dst_lim4) dst4[gi] = tile4[(row << 5) + cp];
    }
}

// Kernel B: stages step=128..4096 on rows {rres + 64*j}, j=0..63.
// Same staged+guarded I/O; register-resident core; k=(rres+64*(j mod h))*(32/h).
template <int REAL_OUT>
__global__ __launch_bounds__(256) void fft_hi(const float* __restrict__ w,
                                              const float4* __restrict__ src4,
                                              float4* __restrict__ dst4,
                                              unsigned src_lim4,
                                              unsigned dst_lim4) {
    __shared__ __align__(16) float2 tile[64 * 64];
    const int t    = threadIdx.x;
    const int c0   = (blockIdx.x & 63) << 6;
    const int rres = blockIdx.x >> 6;

    float4* tile4 = (float4*)tile;
    // Stage-in (round-3 exact): tile row j <- global row rres + 64*j.
#pragma unroll
    for (int l = 0; l < 8; ++l) {
        int idx = l * 256 + t;
        int j   = idx >> 5;
        int cp  = idx & 31;
        size_t gi = (size_t)(rres + (j << 6)) * 2048 + (c0 >> 1) + cp;
        tile4[(j << 5) + cp] = (gi < src_lim4) ? src4[gi]
                                               : make_float4(0.f, 0.f, 0.f, 0.f);
    }
    __syncthreads();                               // barrier 1

    const int c  = t & 63;
    const int pb = t >> 6;

    float ar[16], ai[16];
#pragma unroll
    for (int m = 0; m < 16; ++m) {
        float2 v = tile[(16 * pb + m) * 64 + c];
        ar[m] = v.x; ai[m] = v.y;
    }

    // Phase 1: h = 1,2,4,8 (global steps 128..1024).
#pragma unroll
    for (int h = 1; h <= 8; h <<= 1) {
        const int step = h << 1;
        const int kmul = 32 / h;
#pragma unroll
        for (int r = 0; r < h; ++r) {
            const int k = (rres + 64 * r) * kmul;
            float s, cs;
            const float wk = w[(size_t)k * 4096 + c0 + c];
            __sincosf(NEG_TWOPI * ((float)k * (1.f / 4096.f)) * wk, &s, &cs);
#pragma unroll
            for (int b = 0; b < 8 / h; ++b) {
                const int mt = b * step + r;
                bf(ar[mt], ai[mt], ar[mt + h], ai[mt + h], s, cs);
            }
        }
    }

    // Exchange.
#pragma unroll
    for (int m = 0; m < 16; ++m)
        tile[(16 * pb + m) * 64 + c] = make_float2(ar[m], ai[m]);
    __syncthreads();                               // barrier 2
#pragma unroll
    for (int m = 0; m < 16; ++m) {
        float2 v = tile[(pb + 4 * m) * 64 + c];
        ar[m] = v.x; ai[m] = v.y;
    }

    // Phase 2: global steps 2048 (pairs m,m+4) and 4096 (pairs m,m+8).
#pragma unroll
    for (int rm = 0; rm < 4; ++rm) {
        const int j = pb + 4 * rm;
        const int k = (rres + 64 * j) * 2;
        float s, cs;
        const float wk = w[(size_t)k * 4096 + c0 + c];
        __sincosf(NEG_TWOPI * ((float)k * (1.f / 4096.f)) * wk, &s, &cs);
#pragma unroll
        for (int b = 0; b < 2; ++b) {
            const int mt = b * 8 + rm;
            bf(ar[mt], ai[mt], ar[mt + 4], ai[mt + 4], s, cs);
        }
    }
#pragma unroll
    for (int m = 0; m < 8; ++m) {
        const int j = pb + 4 * m;
        const int k = rres + 64 * j;
        float s, cs;
        const float wk = w[(size_t)k * 4096 + c0 + c];
        __sincosf(NEG_TWOPI * ((float)k * (1.f / 4096.f)) * wk, &s, &cs);
        bf(ar[m], ai[m], ar[m + 8], ai[m + 8], s, cs);
    }

#pragma unroll
    for (int m = 0; m < 16; ++m)
        tile[(pb + 4 * m) * 64 + c] = make_float2(ar[m], ai[m]);
    __syncthreads();                               // barrier 3

    if (REAL_OUT) {
        // Round-3 exact real-part stage-out: out = N*N floats, row-major.
#pragma unroll
        for (int l = 0; l < 4; ++l) {
            int idx = l * 256 + t;                 // 0..1023
            int j   = idx >> 4;
            int g   = idx & 15;
            float4 v;
            v.x = tile[(j << 6) + 4 * g + 0].x;
            v.y = tile[(j << 6) + 4 * g + 1].x;
            v.z = tile[(j << 6) + 4 * g + 2].x;
            v.w = tile[(j << 6) + 4 * g + 3].x;
            size_t gi = (size_t)(rres + (j << 6)) * 1024 + (c0 >> 2) + g;
            if (gi < dst_lim4) dst4[gi] = v;
        }
    } else {
#pragma unroll
        for (int l = 0; l < 8; ++l) {
            int idx = l * 256 + t;
            int j   = idx >> 5;
            int cp  = idx & 31;
            size_t gi = (size_t)(rres + (j << 6)) * 2048 + (c0 >> 1) + cp;
            if (gi < dst_lim4) dst4[gi] = tile4[(j << 5) + cp];
        }
    }
}

extern "C" void kernel_launch(void* const* d_in, const int* in_sizes, int n_in,
                              void* d_out, int out_size, void* d_ws, size_t ws_size,
                              hipStream_t stream) {
    const float* x = (const float*)d_in[0];
    const float* w = (const float*)d_in[1];
    const long long NN = 4096LL * 4096LL;

    if ((long long)out_size >= 2 * NN) {
        // d_out = interleaved complex (2*N*N floats): compute in-place.
        float4* o4 = (float4*)d_out;
        unsigned lim4 = (unsigned)(out_size / 4);
        fft_lo<<<4096, 256, 0, stream>>>(x, w, o4, lim4);
        fft_hi<0><<<4096, 256, 0, stream>>>(w, o4, o4, lim4, lim4);
    } else {
        // Confirmed world: d_out = N*N floats (real part). Complex
        // intermediate in d_ws (>= 2*N*N floats, verified round 3).
        float4* ws4 = (float4*)d_ws;
        unsigned ws_lim4  = (unsigned)(ws_size / 16);
        unsigned out_lim4 = (unsigned)(out_size / 4);
        fft_lo<<<4096, 256, 0, stream>>>(x, w, ws4, ws_lim4);
        fft_hi<1><<<4096, 256, 0, stream>>>(w, (const float4*)ws4, (float4*)d_out,
                                            ws_lim4, out_lim4);
    }
}